// Round 8
// baseline (3956.119 us; speedup 1.0000x reference)
//
#include <hip/hip_runtime.h>
#include <hip/hip_bf16.h>

#define VSZ   32000
#define DSZ   768
#define HN    12
#define HIDSZ 3072
#define NL    2
#define CN    2
#define RR    8
#define SCALEF 2.0f
#define BBATCH 64
#define SSEQ  512
#define HDIM  64
#define NTOK  (BBATCH*SSEQ)   // 32768
#define QKVM  (3*DSZ)         // 2304 — stacked QKV output width

typedef __attribute__((ext_vector_type(8))) short bf16x8;   // 8 bf16 (4 VGPRs)
typedef __attribute__((ext_vector_type(4))) float floatx4;

__device__ __forceinline__ unsigned short f2bf_raw(float f) {
    __hip_bfloat16 h = __float2bfloat16(f);
    return __builtin_bit_cast(unsigned short, h);
}
__device__ __forceinline__ float bf2f(__hip_bfloat16 h) {
    return __bfloat162float(h);
}

// ---------------------------------------------------------------------------
// Embedding -> bf16 x
// ---------------------------------------------------------------------------
__global__ __launch_bounds__(256) void embed_kernel(
    const int* __restrict__ tokens, const float* __restrict__ embW,
    const float* __restrict__ embA, const float* __restrict__ embB,
    __hip_bfloat16* __restrict__ xb)
{
    int n = blockIdx.x;            // n = s*B + b
    int s = n / BBATCH, b = n % BBATCH;
    int tok = tokens[b * SSEQ + s];
    __shared__ float a[RR];
    if (threadIdx.x < RR) a[threadIdx.x] = embA[(size_t)threadIdx.x * VSZ + tok];
    __syncthreads();
    for (int d = threadIdx.x; d < DSZ; d += 256) {
        float val = embW[(size_t)tok * DSZ + d];
        float lo = 0.f;
        #pragma unroll
        for (int r = 0; r < RR; ++r) lo += a[r] * embB[d * RR + r];
        xb[(size_t)n * DSZ + d] = __float2bfloat16(val + SCALEF * lo);
    }
}

// ---------------------------------------------------------------------------
// Effective weight (LoRA folded) -> bf16.  grid = (K/256, M)
// ---------------------------------------------------------------------------
__global__ __launch_bounds__(256) void weff_kernel(
    const float* __restrict__ W, const float* __restrict__ A,
    const float* __restrict__ Bm, __hip_bfloat16* __restrict__ Weff, int K)
{
    int i = blockIdx.x * 256 + threadIdx.x;
    int o = blockIdx.y;
    float acc = W[(size_t)o * K + i];
    #pragma unroll
    for (int r = 0; r < RR; ++r)
        acc += SCALEF * Bm[o * RR + r] * A[(size_t)r * K + i];
    Weff[(size_t)o * K + i] = __float2bfloat16(acc);
}

__global__ __launch_bounds__(256) void biascat_kernel(
    const float* __restrict__ b0, const float* __restrict__ b1v,
    const float* __restrict__ b2v, float* __restrict__ out)
{
    int t = blockIdx.y * 256 + threadIdx.x;   // 0..767
    const float* src = (blockIdx.x == 0) ? b0 : (blockIdx.x == 1) ? b1v : b2v;
    out[blockIdx.x * DSZ + t] = src[t];
}

// ---------------------------------------------------------------------------
// bf16 MFMA GEMM, LDS-FREE: Y[n,m] = bf16( X@W^T + bias (+ res) ), opt relu.
// 128x128 tile, 256 thr = 4 waves (2x2), each wave 64x64 via 4x4 MFMA
// 16x16x32. A/B fragments load DIRECTLY from global (L2): lanes
// {fm,fm+16,fm+32,fm+48} cover one 64B line of a row -> line-coalesced.
// No LDS, no barriers; waves fully independent (attn-kernel pattern).
// ---------------------------------------------------------------------------
#define GT 128

template<bool RELU, bool ADDRES>
__global__ __launch_bounds__(256) void mgemm_kernel(
    const __hip_bfloat16* __restrict__ X, const __hip_bfloat16* __restrict__ W,
    const float* __restrict__ bias, const __hip_bfloat16* __restrict__ res,
    __hip_bfloat16* __restrict__ Y, int K, int ldx, int ldy)
{
    const int t    = threadIdx.x;
    const int n0   = blockIdx.x * GT;
    const int m0   = blockIdx.y * GT;
    const int wv   = t >> 6;
    const int lane = t & 63;
    const int wr   = (wv >> 1) * 64;   // wave row offset in tile
    const int wc   = (wv & 1) * 64;    // wave col offset in tile
    const int fm   = lane & 15;        // fragment free index
    const int fq   = lane >> 4;        // quad 0..3

    floatx4 acc[4][4];
    #pragma unroll
    for (int i = 0; i < 4; ++i)
        #pragma unroll
        for (int j = 0; j < 4; ++j)
            acc[i][j] = (floatx4){0.f, 0.f, 0.f, 0.f};

    // lane's A/B fragment row bases (global)
    const unsigned short* Xg =
        (const unsigned short*)X + (size_t)(n0 + wr + fm) * ldx + fq * 8;
    const unsigned short* Wg =
        (const unsigned short*)W + (size_t)(m0 + wc + fm) * K + fq * 8;
    const size_t xstep = (size_t)16 * ldx;   // +16 rows
    const size_t wstep = (size_t)16 * K;

    #pragma unroll 2
    for (int k0 = 0; k0 < K; k0 += 32) {
        bf16x8 af[4], bfr[4];
        #pragma unroll
        for (int i = 0; i < 4; ++i)
            af[i]  = *(const bf16x8*)(Xg + (size_t)i * xstep + k0);
        #pragma unroll
        for (int j = 0; j < 4; ++j)
            bfr[j] = *(const bf16x8*)(Wg + (size_t)j * wstep + k0);
        #pragma unroll
        for (int i = 0; i < 4; ++i)
            #pragma unroll
            for (int j = 0; j < 4; ++j)
                acc[i][j] = __builtin_amdgcn_mfma_f32_16x16x32_bf16(
                    af[i], bfr[j], acc[i][j], 0, 0, 0);
    }

    // epilogue: D row (token) = wr + i*16 + fq*4 + r ; D col (feat) = wc + j*16 + fm
    #pragma unroll
    for (int j = 0; j < 4; ++j) {
        int col = m0 + wc + j * 16 + fm;
        float bj = bias[col];
        #pragma unroll
        for (int i = 0; i < 4; ++i) {
            int row = n0 + wr + i * 16 + fq * 4;
            #pragma unroll
            for (int r = 0; r < 4; ++r) {
                float v = acc[i][j][r] + bj;
                if (RELU) v = fmaxf(v, 0.f);
                size_t off = (size_t)(row + r) * ldy + col;
                if (ADDRES) v += bf2f(res[off]);
                Y[off] = __float2bfloat16(v);
            }
        }
    }
}

// ---------------------------------------------------------------------------
// MFMA attention over the BATCH axis. qkvb bf16 rows stride QKVM: [Q|K|V].
// Block = one (s',h), 4 waves; wave w owns score rows 16w..16w+15.
// Output bf16 -> aob (stride DSZ). grid = schunk*HN.
// ---------------------------------------------------------------------------
__global__ __launch_bounds__(256) void attn_kernel(
    const __hip_bfloat16* __restrict__ qkvb, __hip_bfloat16* __restrict__ aob)
{
    __shared__ __align__(16) unsigned short Vt[64][72];      // Vt[d][c] = V[c][d]
    __shared__ __align__(16) unsigned short Ps[4][16][72];   // per-wave P rows
    const int t    = threadIdx.x;
    const int wv   = t >> 6;
    const int lane = t & 63;
    const int fm   = lane & 15;
    const int fq   = lane >> 4;
    const int sp   = blockIdx.x / HN;
    const int h    = blockIdx.x % HN;
    const unsigned short* qg =
        (const unsigned short*)qkvb + (size_t)sp * BBATCH * QKVM + h * HDIM;

    // ---- stage V transposed: thread (c=lane, d0=wv*16) reads V[c][d0..d0+15]
    {
        const int c = lane, d0 = wv * 16;
        const unsigned short* vrow = qg + 2 * DSZ + (size_t)c * QKVM + d0;
        bf16x8 v0 = *(const bf16x8*)vrow;
        bf16x8 v1 = *(const bf16x8*)(vrow + 8);
        #pragma unroll
        for (int i = 0; i < 8; ++i) {
            Vt[d0 + i][c]     = (unsigned short)v0[i];
            Vt[d0 + 8 + i][c] = (unsigned short)v1[i];
        }
    }

    // ---- Q A-frags (own 16 rows) and K B-frags (all 64 cols), direct global
    const unsigned short* qrow = qg + (size_t)(wv * 16 + fm) * QKVM + fq * 8;
    bf16x8 af0 = *(const bf16x8*)qrow;
    bf16x8 af1 = *(const bf16x8*)(qrow + 32);
    bf16x8 bk0[4], bk1[4];
    #pragma unroll
    for (int jt = 0; jt < 4; ++jt) {
        const unsigned short* krow = qg + DSZ + (size_t)(jt * 16 + fm) * QKVM + fq * 8;
        bk0[jt] = *(const bf16x8*)krow;
        bk1[jt] = *(const bf16x8*)(krow + 32);
    }

    // ---- scores: 16x64 per wave, fp32 acc
    floatx4 sc[4];
    #pragma unroll
    for (int jt = 0; jt < 4; ++jt) sc[jt] = (floatx4){0.f, 0.f, 0.f, 0.f};
    #pragma unroll
    for (int jt = 0; jt < 4; ++jt) {
        sc[jt] = __builtin_amdgcn_mfma_f32_16x16x32_bf16(af0, bk0[jt], sc[jt], 0, 0, 0);
        sc[jt] = __builtin_amdgcn_mfma_f32_16x16x32_bf16(af1, bk1[jt], sc[jt], 0, 0, 0);
    }
    #pragma unroll
    for (int jt = 0; jt < 4; ++jt)
        #pragma unroll
        for (int r = 0; r < 4; ++r) sc[jt][r] *= 0.125f;

    // ---- softmax per row (row = fq*4+r, spread over 16 lanes x 4 jt)
    float pr[4][4];
    #pragma unroll
    for (int r = 0; r < 4; ++r) {
        float m = fmaxf(fmaxf(sc[0][r], sc[1][r]), fmaxf(sc[2][r], sc[3][r]));
        #pragma unroll
        for (int msk = 1; msk < 16; msk <<= 1) m = fmaxf(m, __shfl_xor(m, msk, 64));
        float s = 0.f;
        #pragma unroll
        for (int jt = 0; jt < 4; ++jt) { pr[jt][r] = __expf(sc[jt][r] - m); s += pr[jt][r]; }
        #pragma unroll
        for (int msk = 1; msk < 16; msk <<= 1) s += __shfl_xor(s, msk, 64);
        float inv = 1.f / s;
        #pragma unroll
        for (int jt = 0; jt < 4; ++jt) pr[jt][r] *= inv;
    }

    // ---- P -> LDS (C-layout -> A-layout round trip), bf16
    #pragma unroll
    for (int jt = 0; jt < 4; ++jt)
        #pragma unroll
        for (int r = 0; r < 4; ++r)
            Ps[wv][fq * 4 + r][jt * 16 + fm] = f2bf_raw(pr[jt][r]);

    __syncthreads();   // Vt (cross-wave) ready; Ps is wave-local

    // ---- PV: A = P (own rows), B = Vt
    bf16x8 ap0 = *(const bf16x8*)&Ps[wv][fm][fq * 8];
    bf16x8 ap1 = *(const bf16x8*)&Ps[wv][fm][32 + fq * 8];
    floatx4 ov[4];
    #pragma unroll
    for (int jt = 0; jt < 4; ++jt) ov[jt] = (floatx4){0.f, 0.f, 0.f, 0.f};
    #pragma unroll
    for (int jt = 0; jt < 4; ++jt) {
        bf16x8 bv0 = *(const bf16x8*)&Vt[jt * 16 + fm][fq * 8];
        bf16x8 bv1 = *(const bf16x8*)&Vt[jt * 16 + fm][32 + fq * 8];
        ov[jt] = __builtin_amdgcn_mfma_f32_16x16x32_bf16(ap0, bv0, ov[jt], 0, 0, 0);
        ov[jt] = __builtin_amdgcn_mfma_f32_16x16x32_bf16(ap1, bv1, ov[jt], 0, 0, 0);
    }

    // ---- write O bf16: row b = 16wv + 4fq + r, col d = jt*16+fm
    __hip_bfloat16* obase = aob + ((size_t)sp * BBATCH + wv * 16 + fq * 4) * DSZ + h * HDIM;
    #pragma unroll
    for (int jt = 0; jt < 4; ++jt)
        #pragma unroll
        for (int r = 0; r < 4; ++r)
            obase[(size_t)r * DSZ + jt * 16 + fm] = __float2bfloat16(ov[jt][r]);
}

// ---------------------------------------------------------------------------
// LayerNorm: src bf16 -> dst bf16 (separate buffers), fp32 stats.
// ---------------------------------------------------------------------------
__device__ __forceinline__ float block_sum256(float vsum, volatile float* red) {
    #pragma unroll
    for (int off = 32; off > 0; off >>= 1) vsum += __shfl_down(vsum, off, 64);
    if ((threadIdx.x & 63) == 0) red[threadIdx.x >> 6] = vsum;
    __syncthreads();
    return red[0] + red[1] + red[2] + red[3];
}

__global__ __launch_bounds__(256) void ln_kernel(
    const __hip_bfloat16* __restrict__ src, __hip_bfloat16* __restrict__ dst,
    const float* __restrict__ g, const float* __restrict__ be)
{
    __shared__ float red1[4];
    __shared__ float red2[4];
    const int n = blockIdx.x;
    const int t = threadIdx.x;
    const __hip_bfloat16* row = src + (size_t)n * DSZ;
    __hip_bfloat16* orow = dst + (size_t)n * DSZ;
    float v0 = bf2f(row[t]), v1 = bf2f(row[t + 256]), v2 = bf2f(row[t + 512]);
    float total = block_sum256(v0 + v1 + v2, red1);
    float mean = total * (1.0f / DSZ);
    float d0 = v0 - mean, d1 = v1 - mean, d2 = v2 - mean;
    __syncthreads();
    float var = block_sum256(d0 * d0 + d1 * d1 + d2 * d2, red2) * (1.0f / DSZ);
    float rstd = rsqrtf(var + 1e-5f);
    orow[t]       = __float2bfloat16(d0 * rstd * g[t]       + be[t]);
    orow[t + 256] = __float2bfloat16(d1 * rstd * g[t + 256] + be[t + 256]);
    orow[t + 512] = __float2bfloat16(d2 * rstd * g[t + 512] + be[t + 512]);
}

// ---------------------------------------------------------------------------
__global__ __launch_bounds__(256) void meanS_kernel(
    const __hip_bfloat16* __restrict__ x, float* __restrict__ xm)
{
    int idx = blockIdx.x * 256 + threadIdx.x;   // over B*D, d fastest
    int b = idx / DSZ, d = idx % DSZ;
    float acc = 0.f;
    for (int s = 0; s < SSEQ; ++s)
        acc += bf2f(x[((size_t)s * BBATCH + b) * DSZ + d]);
    xm[idx] = acc * (1.0f / SSEQ);
}

__global__ __launch_bounds__(128) void fc_kernel(
    const float* __restrict__ xm, const float* __restrict__ fcW,
    const float* __restrict__ fcb, const float* __restrict__ fcA,
    const float* __restrict__ fcBm, float* __restrict__ out)
{
    int t = threadIdx.x;
    if (t >= BBATCH * CN) return;
    int b = t / CN, c = t % CN;
    float acc = fcb[c];
    float lora[RR];
    #pragma unroll
    for (int r = 0; r < RR; ++r) lora[r] = 0.f;
    for (int d = 0; d < DSZ; ++d) {
        float xv = xm[b * DSZ + d];
        acc += xv * fcW[c * DSZ + d];
        #pragma unroll
        for (int r = 0; r < RR; ++r) lora[r] += xv * fcA[r * DSZ + d];
    }
    float lo = 0.f;
    #pragma unroll
    for (int r = 0; r < RR; ++r) lo += lora[r] * fcBm[c * RR + r];
    out[b * CN + c] = acc + SCALEF * lo;
}

// ---------------------------------------------------------------------------
extern "C" void kernel_launch(void* const* d_in, const int* in_sizes, int n_in,
                              void* d_out, int out_size, void* d_ws, size_t ws_size,
                              hipStream_t stream) {
    const int*   tokens = (const int*)  d_in[0];
    const float* embW   = (const float*)d_in[1];
    const float* embA   = (const float*)d_in[2];
    const float* embB   = (const float*)d_in[3];
    const float* Wq = (const float*)d_in[4],  *bq = (const float*)d_in[5],
               * Aq = (const float*)d_in[6],  *Bq = (const float*)d_in[7];
    const float* Wk = (const float*)d_in[8],  *bk = (const float*)d_in[9],
               * Ak = (const float*)d_in[10], *Bk = (const float*)d_in[11];
    const float* Wv = (const float*)d_in[12], *bv = (const float*)d_in[13],
               * Av = (const float*)d_in[14], *Bv = (const float*)d_in[15];
    const float* Wo = (const float*)d_in[16], *bo = (const float*)d_in[17],
               * Ao = (const float*)d_in[18], *Bo = (const float*)d_in[19];
    const float* W1 = (const float*)d_in[20], *b1 = (const float*)d_in[21],
               * A1 = (const float*)d_in[22], *B1 = (const float*)d_in[23];
    const float* W2 = (const float*)d_in[24], *b2 = (const float*)d_in[25],
               * A2 = (const float*)d_in[26], *B2 = (const float*)d_in[27];
    const float* g1 = (const float*)d_in[28], *be1 = (const float*)d_in[29];
    const float* g2 = (const float*)d_in[30], *be2 = (const float*)d_in[31];
    const float* fcW = (const float*)d_in[32], *fcb = (const float*)d_in[33];
    const float* fcA = (const float*)d_in[34], *fcBm = (const float*)d_in[35];

    const size_t ND = (size_t)NTOK * DSZ;

    // ---- workspace layout (float units; all sections multiple of 4) ------
    const size_t X_F    = ND / 2;                       // bf16 x (LN out / residual base)
    const size_t XT_F   = ND / 2;                       // bf16 xt (pre-LN sum)
    const size_t WQKV_F = (size_t)QKVM * DSZ / 2;
    const size_t WO_F   = (size_t)DSZ * DSZ / 2;
    const size_t WF1_F  = (size_t)HIDSZ * DSZ / 2;
    const size_t WF2_F  = (size_t)DSZ * HIDSZ / 2;
    const size_t BQKV_F = 2304;
    const size_t XM_F   = (size_t)BBATCH * DSZ;
    const size_t fixedF = X_F + XT_F + WQKV_F + WO_F + WF1_F + WF2_F + BQKV_F + XM_F;
    const size_t availF = ws_size / 4;

    int schunk = 2;
    const int cand[6] = {512, 256, 128, 64, 32, 16};
    for (int i = 0; i < 6; ++i) {
        // per-chunk: bf16 qkv (Nc*2304) + bf16 aob (Nc*768) == bf16 h (Nc*3072)
        size_t chunkF = (size_t)cand[i] * BBATCH * (HIDSZ / 2);
        if (fixedF + chunkF <= availF) { schunk = cand[i]; break; }
    }
    const int Nc = schunk * BBATCH;
    const int nchunk = SSEQ / schunk;

    float* p = (float*)d_ws;
    __hip_bfloat16* x  = (__hip_bfloat16*)p;     p += X_F;
    __hip_bfloat16* xt = (__hip_bfloat16*)p;     p += XT_F;
    __hip_bfloat16* wqkvb = (__hip_bfloat16*)p;  p += WQKV_F;
    __hip_bfloat16* wob   = (__hip_bfloat16*)p;  p += WO_F;
    __hip_bfloat16* wf1b  = (__hip_bfloat16*)p;  p += WF1_F;
    __hip_bfloat16* wf2b  = (__hip_bfloat16*)p;  p += WF2_F;
    float* bqkv = p;                             p += BQKV_F;
    float* xm   = p;                             p += XM_F;
    __hip_bfloat16* cb16 = (__hip_bfloat16*)p;   // chunk: qkvb|aob, later h
    __hip_bfloat16* qkvb = cb16;
    __hip_bfloat16* aob  = cb16 + (size_t)Nc * QKVM;
    __hip_bfloat16* hb   = cb16;

    embed_kernel<<<NTOK, 256, 0, stream>>>(tokens, embW, embA, embB, x);

    for (int l = 0; l < NL; ++l) {
        const size_t oDD = (size_t)l * DSZ * DSZ;
        const size_t oDH = (size_t)l * HIDSZ * DSZ;
        const size_t oRD = (size_t)l * RR * DSZ;
        const size_t oRH = (size_t)l * RR * HIDSZ;
        const size_t oDR = (size_t)l * DSZ * RR;
        const size_t oHR = (size_t)l * HIDSZ * RR;

        weff_kernel<<<dim3(3, DSZ), 256, 0, stream>>>(Wq + oDD, Aq + oRD, Bq + oDR, wqkvb, DSZ);
        weff_kernel<<<dim3(3, DSZ), 256, 0, stream>>>(Wk + oDD, Ak + oRD, Bk + oDR, wqkvb + (size_t)DSZ * DSZ, DSZ);
        weff_kernel<<<dim3(3, DSZ), 256, 0, stream>>>(Wv + oDD, Av + oRD, Bv + oDR, wqkvb + (size_t)2 * DSZ * DSZ, DSZ);
        biascat_kernel<<<dim3(3, 3), 256, 0, stream>>>(bq + (size_t)l * DSZ, bk + (size_t)l * DSZ, bv + (size_t)l * DSZ, bqkv);
        weff_kernel<<<dim3(3, DSZ), 256, 0, stream>>>(Wo + oDD, Ao + oRD, Bo + oDR, wob, DSZ);
        weff_kernel<<<dim3(3, HIDSZ), 256, 0, stream>>>(W1 + oDH, A1 + oRD, B1 + oHR, wf1b, DSZ);
        weff_kernel<<<dim3(12, DSZ), 256, 0, stream>>>(W2 + oDH, A2 + oRH, B2 + oDR, wf2b, HIDSZ);

        const float* bo_l = bo + (size_t)l * DSZ;
        const float* b1_l = b1 + (size_t)l * HIDSZ;
        const float* b2_l = b2 + (size_t)l * DSZ;

        for (int c = 0; c < nchunk; ++c) {
            __hip_bfloat16* xc  = x  + (size_t)c * Nc * DSZ;
            __hip_bfloat16* xtc = xt + (size_t)c * Nc * DSZ;

            // QKV stacked: (Nc x 768) @ (2304 x 768)^T -> bf16 qkvb
            mgemm_kernel<false, false><<<dim3(Nc / GT, QKVM / GT), 256, 0, stream>>>(
                xc, wqkvb, bqkv, nullptr, qkvb, DSZ, DSZ, QKVM);

            attn_kernel<<<schunk * HN, 256, 0, stream>>>(qkvb, aob);

            // O-proj + residual(x) -> xt, then LN1: xt -> x
            mgemm_kernel<false, true><<<dim3(Nc / GT, DSZ / GT), 256, 0, stream>>>(
                aob, wob, bo_l, xc, xtc, DSZ, DSZ, DSZ);
            ln_kernel<<<Nc, 256, 0, stream>>>(xtc, xc, g1 + (size_t)l * DSZ, be1 + (size_t)l * DSZ);

            // FF1 (relu) -> bf16 h (qkv/aob dead, reuse chunk buffer)
            mgemm_kernel<true, false><<<dim3(Nc / GT, HIDSZ / GT), 256, 0, stream>>>(
                xc, wf1b, b1_l, nullptr, hb, DSZ, DSZ, HIDSZ);

            // FF2 + residual(x) -> xt, then LN2: xt -> x
            mgemm_kernel<false, true><<<dim3(Nc / GT, DSZ / GT), 256, 0, stream>>>(
                hb, wf2b, b2_l, xc, xtc, HIDSZ, HIDSZ, DSZ);
            ln_kernel<<<Nc, 256, 0, stream>>>(xtc, xc, g2 + (size_t)l * DSZ, be2 + (size_t)l * DSZ);
        }
    }

    meanS_kernel<<<(BBATCH * DSZ) / 256, 256, 0, stream>>>(x, xm);
    fc_kernel<<<1, 128, 0, stream>>>(xm, fcW, fcb, fcA, fcBm, (float*)d_out);
}